// Round 2
// baseline (1605.508 us; speedup 1.0000x reference)
//
#include <hip/hip_runtime.h>
#include <hip/hip_bf16.h>
#include <stdint.h>

typedef unsigned int uint32;
typedef __attribute__((ext_vector_type(8))) short short8;
typedef __attribute__((ext_vector_type(4))) float f32x4;

#define NB 128
#define NT 256
#define NH 512
#define NE 80
#define NCH 128
#define NL 784
#define NV 500
#define NG4 2048

__device__ __forceinline__ unsigned short f2bf(float f){
  union { float f; unsigned int i; } v; v.f = f;
  unsigned int r = v.i + 0x7FFFu + ((v.i >> 16) & 1u);
  return (unsigned short)(r >> 16);
}
__device__ __forceinline__ float sigf(float x){ return 1.0f/(1.0f + __expf(-x)); }
__device__ __forceinline__ float tanhfast(float x){ return 1.0f - 2.0f/(__expf(2.0f*x)+1.0f); }

// ---------------- K1: mean over L (f32 inputs) ----------------
__global__ void k_mean(const float* __restrict__ lat, float* __restrict__ meanv){
  int b = blockIdx.x;
  int tid = threadIdx.x;          // 256
  int c4 = tid & 31;              // float4 col (4 channels) -> 128 ch
  int part = tid >> 5;            // 0..7
  const float4* row = (const float4*)(lat + (size_t)b*NL*NCH);
  float sx=0.f, sy=0.f, sz=0.f, sw=0.f;
  for (int l=part; l<NL; l+=8){
    float4 v = row[l*32 + c4];
    sx+=v.x; sy+=v.y; sz+=v.z; sw+=v.w;
  }
  __shared__ float red[8][32][4];
  red[part][c4][0]=sx; red[part][c4][1]=sy; red[part][c4][2]=sz; red[part][c4][3]=sw;
  __syncthreads();
  if (part==0){
    float a0=0,a1=0,a2=0,a3=0;
    #pragma unroll
    for (int p=0;p<8;p++){ a0+=red[p][c4][0]; a1+=red[p][c4][1]; a2+=red[p][c4][2]; a3+=red[p][c4][3]; }
    float4 o; o.x=a0*(1.0f/NL); o.y=a1*(1.0f/NL); o.z=a2*(1.0f/NL); o.w=a3*(1.0f/NL);
    ((float4*)meanv)[b*32 + c4] = o;
  }
}

// ---------------- K2: h0/c0/o0 + initial h exchange buffer ----------------
__global__ void k_init(const float* __restrict__ meanv,
    const float* __restrict__ Wh, const float* __restrict__ bh,
    const float* __restrict__ Wc, const float* __restrict__ bc,
    const float* __restrict__ Wo, const float* __restrict__ bo,
    float* __restrict__ c0, float* __restrict__ o0, unsigned short* __restrict__ hbuf0){
  int b = blockIdx.x; int j = threadIdx.x;  // 512 threads
  const float* m = meanv + b*NCH;
  const float4* wh = (const float4*)(Wh + (size_t)j*NCH);
  const float4* wc = (const float4*)(Wc + (size_t)j*NCH);
  const float4* wo = (const float4*)(Wo + (size_t)j*NCH);
  float sh=0.f, sc=0.f, so=0.f;
  for (int c=0; c<NCH/4; c++){
    float4 vh = wh[c], vc = wc[c], vo = wo[c];
    float m0=m[c*4], m1=m[c*4+1], m2=m[c*4+2], m3=m[c*4+3];
    sh += m0*vh.x + m1*vh.y + m2*vh.z + m3*vh.w;
    sc += m0*vc.x + m1*vc.y + m2*vc.z + m3*vc.w;
    so += m0*vo.x + m1*vo.y + m2*vo.z + m3*vo.w;
  }
  float h0 = tanhf(sh + bh[j]);
  c0[b*NH+j] = tanhf(sc + bc[j]);
  o0[b*NH+j] = tanhf(so + bo[j]);
  hbuf0[b*NH+j] = f2bf(h0);
}

// ---------------- K3: per-token gate table = emb @ W_ih[:,512:].T ----------------
__global__ void k_table(const float* __restrict__ emb,
                        const float* __restrict__ Wih,
                        float* __restrict__ table){
  int v = blockIdx.x;
  int n = blockIdx.y*256 + threadIdx.x;
  const float4* wr = (const float4*)(Wih + (size_t)n*(NH+NE) + NH);
  const float4* er = (const float4*)(emb + v*NE);
  float s = 0.f;
  for (int e4=0; e4<NE/4; e4++){
    float4 w = wr[e4], e = er[e4];
    s += w.x*e.x + w.y*e.y + w.z*e.z + w.w*e.w;
  }
  table[(size_t)v*NG4 + n] = s;
}

// ---------------- K4: base = o0 @ W_ih[:,:512].T + b_ih + b_hh ----------------
__global__ void k_base(const float* __restrict__ o0,
                       const float* __restrict__ Wih,
                       const float* __restrict__ bih,
                       const float* __restrict__ bhh,
                       float* __restrict__ base){
  int b = blockIdx.x;
  int n = blockIdx.y*256 + threadIdx.x;
  const float4* o = (const float4*)(o0 + b*NH);
  const float4* wr = (const float4*)(Wih + (size_t)n*(NH+NE));
  float s = bih[n] + bhh[n];
  for (int k4=0;k4<NH/4;k4++){
    float4 w = wr[k4], v = o[k4];
    s += w.x*v.x + w.y*v.y + w.z*v.z + w.w*v.w;
  }
  base[(size_t)b*NG4 + n] = s;
}

// ---------------- K5: sequential LSTM ----------------
// 128 blocks = 8 groups (16 batch rows, XCD-affine via bid&7) x 16 slices (32 hidden units).
// W_hh slice (converted to bf16) lives in VGPRs. h exchanged per step (bf16-packed)
// via double-buffered agent-scope buffer.
#define HBUF_U (NB*(NH/2))   // uints per h buffer

__global__ __launch_bounds__(256, 1) void k_lstm(
    const float* __restrict__ Whh,
    const int* __restrict__ formulas,
    const float* __restrict__ table,
    const float* __restrict__ base,
    const float* __restrict__ c0,
    uint32* hbuf, int* bar,
    float* __restrict__ out)
{
  int bid = blockIdx.x;
  int g = bid & 7, s = bid >> 3;
  int tid = threadIdx.x;
  int lane = tid & 63, w = tid >> 6;
  int b0 = g*16, u0 = s*32;

  __shared__ __align__(16) char h_lds[16*1024];   // [16 rows][512 bf16], XOR-swizzled
  __shared__ float G[16*132 + 4];                 // gate exchange, stride 132 f32

  // ---- B fragments (W_hh slice, f32 -> bf16) into registers: bw[halftile][kstep]
  short8 bw[2][16];
  {
    int krow = (lane >> 4) * 8;
    #pragma unroll
    for (int h2=0; h2<2; h2++){
      int c_loc = w*32 + h2*16 + (lane & 15);              // local col 0..127 (gate = w)
      int wrow = (c_loc >> 5)*NH + u0 + (c_loc & 31);      // W_hh row (gate*512 + unit)
      const float4* p4 = (const float4*)(Whh + (size_t)wrow*NH + krow);
      #pragma unroll
      for (int ks=0; ks<16; ks++){
        float4 lo = p4[ks*8], hi = p4[ks*8+1];             // 8 f32 at k = krow + ks*32
        short8 t;
        t[0]=(short)f2bf(lo.x); t[1]=(short)f2bf(lo.y); t[2]=(short)f2bf(lo.z); t[3]=(short)f2bf(lo.w);
        t[4]=(short)f2bf(hi.x); t[5]=(short)f2bf(hi.y); t[6]=(short)f2bf(hi.z); t[7]=(short)f2bf(hi.w);
        bw[h2][ks] = t;
      }
    }
  }

  // ---- epilogue identity: thread -> (row r_e, unit-pair up)
  int r_e = tid >> 4, up = tid & 15;
  int be = b0 + r_e;
  float cst0 = c0[be*NH + u0 + 2*up];
  float cst1 = c0[be*NH + u0 + 2*up + 1];

  int arow = lane & 15;
  int abyte = arow*1024 + ((lane>>4)*8)*2;
  int aswz = (arow & 7) << 4;

  for (int t=0; t<NT; t++){
    const uint32* hrd = hbuf + (t & 1)*HBUF_U;
    uint32*       hwr = hbuf + ((t+1) & 1)*HBUF_U;

    // ---- stage group's h rows into LDS (swizzled)
    uint32 vals[16];
    #pragma unroll
    for (int it=0; it<16; it++){
      int i = tid + it*256;
      int r = i >> 8, cu = i & 255;
      vals[it] = __hip_atomic_load(&hrd[(b0+r)*(NH/2) + cu],
                                   __ATOMIC_RELAXED, __HIP_MEMORY_SCOPE_AGENT);
    }
    #pragma unroll
    for (int it=0; it<16; it++){
      int i = tid + it*256;
      int r = i >> 8, cu = i & 255;
      *(uint32*)(h_lds + ((r*1024 + cu*4) ^ ((r & 7) << 4))) = vals[it];
    }
    __syncthreads();

    // ---- MFMA: G_slice = h[16,512] @ Wslice.T
    f32x4 acc0 = {0.f,0.f,0.f,0.f}, acc1 = {0.f,0.f,0.f,0.f};
    #pragma unroll
    for (int ks=0; ks<16; ks++){
      short8 a = *(const short8*)(h_lds + ((abyte + ks*64) ^ aswz));
      acc0 = __builtin_amdgcn_mfma_f32_16x16x32_bf16(a, bw[0][ks], acc0, 0, 0, 0);
      acc1 = __builtin_amdgcn_mfma_f32_16x16x32_bf16(a, bw[1][ks], acc1, 0, 0, 0);
    }

    // ---- scatter acc -> G  (D: row=(lane>>4)*4+r, col=lane&15 per tile)
    {
      int rbase = (lane>>4)*4;
      int col0 = (w*2+0)*16 + (lane&15);
      int col1 = (w*2+1)*16 + (lane&15);
      #pragma unroll
      for (int r4=0;r4<4;r4++){
        G[(rbase+r4)*132 + col0] = acc0[r4];
        G[(rbase+r4)*132 + col1] = acc1[r4];
      }
    }
    __syncthreads();

    // ---- fused gate epilogue (2 units per thread), c-state in regs
    {
      int tok = formulas[be*NT + t];
      const float* tb = table + (size_t)tok*NG4 + u0 + 2*up;
      const float* bs = base + (size_t)be*NG4 + u0 + 2*up;
      const float* Gr = G + r_e*132 + 2*up;
      float hn0, hn1;
      {
        float gi = Gr[0*32+0] + tb[0*NH+0] + bs[0*NH+0];
        float gf = Gr[1*32+0] + tb[1*NH+0] + bs[1*NH+0];
        float gg = Gr[2*32+0] + tb[2*NH+0] + bs[2*NH+0];
        float go = Gr[3*32+0] + tb[3*NH+0] + bs[3*NH+0];
        float cn = sigf(gf)*cst0 + sigf(gi)*tanhfast(gg);
        cst0 = cn;
        hn0 = sigf(go) * tanhfast(cn);
      }
      {
        float gi = Gr[0*32+1] + tb[0*NH+1] + bs[0*NH+1];
        float gf = Gr[1*32+1] + tb[1*NH+1] + bs[1*NH+1];
        float gg = Gr[2*32+1] + tb[2*NH+1] + bs[2*NH+1];
        float go = Gr[3*32+1] + tb[3*NH+1] + bs[3*NH+1];
        float cn = sigf(gf)*cst1 + sigf(gi)*tanhfast(gg);
        cst1 = cn;
        hn1 = sigf(go) * tanhfast(cn);
      }
      float2 ov; ov.x = hn0; ov.y = hn1;
      *(float2*)(out + ((size_t)be*NT + t)*NH + u0 + 2*up) = ov;
      uint32 packed = (uint32)f2bf(hn0) | ((uint32)f2bf(hn1) << 16);
      __hip_atomic_store(&hwr[be*(NH/2) + (u0/2 + up)], packed,
                         __ATOMIC_RELAXED, __HIP_MEMORY_SCOPE_AGENT);
    }
    __syncthreads();   // all waves' stores retired (vmcnt 0) before arrive

    // ---- per-group barrier (16 blocks), monotonic counter
    if (t != NT-1){
      if (tid == 0){
        __hip_atomic_fetch_add(&bar[g], 1, __ATOMIC_RELEASE, __HIP_MEMORY_SCOPE_AGENT);
        int tgt = 16*(t+1);
        int guard = 0;
        while (__hip_atomic_load(&bar[g], __ATOMIC_ACQUIRE, __HIP_MEMORY_SCOPE_AGENT) < tgt){
          __builtin_amdgcn_s_sleep(1);
          if (++guard > (1<<24)) break;   // bail out instead of hanging
        }
      }
      __syncthreads();
    }
  }
}

extern "C" void kernel_launch(void* const* d_in, const int* in_sizes, int n_in,
                              void* d_out, int out_size, void* d_ws, size_t ws_size,
                              hipStream_t stream) {
  const float* lat      = (const float*)d_in[0];
  const int*   formulas = (const int*)d_in[1];
  const float* emb      = (const float*)d_in[2];
  const float* Wih      = (const float*)d_in[3];
  const float* bih      = (const float*)d_in[4];
  const float* Whh      = (const float*)d_in[5];
  const float* bhh      = (const float*)d_in[6];
  const float* Wh       = (const float*)d_in[7];
  const float* bh       = (const float*)d_in[8];
  const float* Wc       = (const float*)d_in[9];
  const float* bc       = (const float*)d_in[10];
  const float* Wo       = (const float*)d_in[11];
  const float* bo       = (const float*)d_in[12];
  float* out = (float*)d_out;

  char* ws = (char*)d_ws;
  float* meanv = (float*)ws;  ws += (size_t)NB*NCH*4;        // 64 KB
  float* c0    = (float*)ws;  ws += (size_t)NB*NH*4;         // 256 KB
  float* o0    = (float*)ws;  ws += (size_t)NB*NH*4;         // 256 KB
  float* table = (float*)ws;  ws += (size_t)NV*NG4*4;        // 4 MB
  float* base  = (float*)ws;  ws += (size_t)NB*NG4*4;        // 1 MB
  uint32* hbuf = (uint32*)ws; ws += (size_t)2*HBUF_U*4;      // 256 KB (double-buffered)
  int*   bar   = (int*)ws;    ws += 256;

  hipMemsetAsync(bar, 0, 256, stream);
  k_mean <<<NB, 256, 0, stream>>>(lat, meanv);
  k_init <<<NB, NH, 0, stream>>>(meanv, Wh, bh, Wc, bc, Wo, bo, c0, o0, (unsigned short*)hbuf);
  k_table<<<dim3(NV, 8), 256, 0, stream>>>(emb, Wih, table);
  k_base <<<dim3(NB, 8), 256, 0, stream>>>(o0, Wih, bih, bhh, base);
  k_lstm <<<NB, 256, 0, stream>>>(Whh, formulas, table, base, c0, hbuf, bar, out);
}

// Round 3
// 712.639 us; speedup vs baseline: 2.2529x; 2.2529x over previous
//
#include <hip/hip_runtime.h>
#include <hip/hip_bf16.h>
#include <stdint.h>

typedef unsigned int uint32;
typedef __attribute__((ext_vector_type(8))) short short8;
typedef __attribute__((ext_vector_type(4))) float f32x4;

#define NB 128
#define NT 256
#define NH 512
#define NE 80
#define NCH 128
#define NL 784
#define NV 500
#define NG4 2048

__device__ __forceinline__ unsigned short f2bf(float f){
  union { float f; unsigned int i; } v; v.f = f;
  unsigned int r = v.i + 0x7FFFu + ((v.i >> 16) & 1u);
  return (unsigned short)(r >> 16);
}
__device__ __forceinline__ float sigf(float x){ return 1.0f/(1.0f + __expf(-x)); }
__device__ __forceinline__ float tanhfast(float x){ return 1.0f - 2.0f/(__expf(2.0f*x)+1.0f); }

// ---------------- K1: mean over L (f32 inputs) ----------------
__global__ void k_mean(const float* __restrict__ lat, float* __restrict__ meanv){
  int b = blockIdx.x;
  int tid = threadIdx.x;          // 256
  int c4 = tid & 31;              // float4 col (4 channels) -> 128 ch
  int part = tid >> 5;            // 0..7
  const float4* row = (const float4*)(lat + (size_t)b*NL*NCH);
  float sx=0.f, sy=0.f, sz=0.f, sw=0.f;
  for (int l=part; l<NL; l+=8){
    float4 v = row[l*32 + c4];
    sx+=v.x; sy+=v.y; sz+=v.z; sw+=v.w;
  }
  __shared__ float red[8][32][4];
  red[part][c4][0]=sx; red[part][c4][1]=sy; red[part][c4][2]=sz; red[part][c4][3]=sw;
  __syncthreads();
  if (part==0){
    float a0=0,a1=0,a2=0,a3=0;
    #pragma unroll
    for (int p=0;p<8;p++){ a0+=red[p][c4][0]; a1+=red[p][c4][1]; a2+=red[p][c4][2]; a3+=red[p][c4][3]; }
    float4 o; o.x=a0*(1.0f/NL); o.y=a1*(1.0f/NL); o.z=a2*(1.0f/NL); o.w=a3*(1.0f/NL);
    ((float4*)meanv)[b*32 + c4] = o;
  }
}

// ---------------- K2: h0/c0/o0 + initial h exchange buffer ----------------
__global__ void k_init(const float* __restrict__ meanv,
    const float* __restrict__ Wh, const float* __restrict__ bh,
    const float* __restrict__ Wc, const float* __restrict__ bc,
    const float* __restrict__ Wo, const float* __restrict__ bo,
    float* __restrict__ c0, float* __restrict__ o0, unsigned short* __restrict__ hbuf0){
  int b = blockIdx.x; int j = threadIdx.x;  // 512 threads
  const float* m = meanv + b*NCH;
  const float4* wh = (const float4*)(Wh + (size_t)j*NCH);
  const float4* wc = (const float4*)(Wc + (size_t)j*NCH);
  const float4* wo = (const float4*)(Wo + (size_t)j*NCH);
  float sh=0.f, sc=0.f, so=0.f;
  for (int c=0; c<NCH/4; c++){
    float4 vh = wh[c], vc = wc[c], vo = wo[c];
    float m0=m[c*4], m1=m[c*4+1], m2=m[c*4+2], m3=m[c*4+3];
    sh += m0*vh.x + m1*vh.y + m2*vh.z + m3*vh.w;
    sc += m0*vc.x + m1*vc.y + m2*vc.z + m3*vc.w;
    so += m0*vo.x + m1*vo.y + m2*vo.z + m3*vo.w;
  }
  float h0 = tanhf(sh + bh[j]);
  c0[b*NH+j] = tanhf(sc + bc[j]);
  o0[b*NH+j] = tanhf(so + bo[j]);
  hbuf0[b*NH+j] = f2bf(h0);
}

// ---------------- K3: per-token gate table = emb @ W_ih[:,512:].T ----------------
__global__ void k_table(const float* __restrict__ emb,
                        const float* __restrict__ Wih,
                        float* __restrict__ table){
  int v = blockIdx.x;
  int n = blockIdx.y*256 + threadIdx.x;
  const float4* wr = (const float4*)(Wih + (size_t)n*(NH+NE) + NH);
  const float4* er = (const float4*)(emb + v*NE);
  float s = 0.f;
  for (int e4=0; e4<NE/4; e4++){
    float4 w = wr[e4], e = er[e4];
    s += w.x*e.x + w.y*e.y + w.z*e.z + w.w*e.w;
  }
  table[(size_t)v*NG4 + n] = s;
}

// ---------------- K4: base = o0 @ W_ih[:,:512].T + b_ih + b_hh ----------------
__global__ void k_base(const float* __restrict__ o0,
                       const float* __restrict__ Wih,
                       const float* __restrict__ bih,
                       const float* __restrict__ bhh,
                       float* __restrict__ base){
  int b = blockIdx.x;
  int n = blockIdx.y*256 + threadIdx.x;
  const float4* o = (const float4*)(o0 + b*NH);
  const float4* wr = (const float4*)(Wih + (size_t)n*(NH+NE));
  float s = bih[n] + bhh[n];
  for (int k4=0;k4<NH/4;k4++){
    float4 w = wr[k4], v = o[k4];
    s += w.x*v.x + w.y*v.y + w.z*v.z + w.w*v.w;
  }
  base[(size_t)b*NG4 + n] = s;
}

// ---------------- K5: sequential LSTM ----------------
// 128 blocks = 8 groups (16 batch rows) x 16 slices (32 hidden units).
// W_hh slice (bf16) in VGPRs. h exchanged per step via double-buffered L3
// buffer with per-block monotonic flags (relaxed-only protocol, no fences).
#define HBUF_U (NB*(NH/2))   // uints per h buffer

__global__ __launch_bounds__(256, 1) void k_lstm(
    const float* __restrict__ Whh,
    const int* __restrict__ formulas,
    const float* __restrict__ table,
    const float* __restrict__ base,
    const float* __restrict__ c0,
    uint32* hbuf, int* flags,
    float* __restrict__ out)
{
  int bid = blockIdx.x;
  int g = bid & 7, s = bid >> 3;
  int tid = threadIdx.x;
  int lane = tid & 63, w = tid >> 6;
  int b0 = g*16, u0 = s*32;

  __shared__ __align__(16) char h_lds[16*1024];   // [16 rows][512 bf16], XOR-swizzled
  __shared__ float G[16*132 + 4];                 // gate exchange, stride 132 f32

  // ---- B fragments (W_hh slice, f32 -> bf16) into registers: bw[halftile][kstep]
  short8 bw[2][16];
  {
    int krow = (lane >> 4) * 8;
    #pragma unroll
    for (int h2=0; h2<2; h2++){
      int c_loc = w*32 + h2*16 + (lane & 15);              // local col 0..127 (gate = w)
      int wrow = (c_loc >> 5)*NH + u0 + (c_loc & 31);      // W_hh row (gate*512 + unit)
      const float4* p4 = (const float4*)(Whh + (size_t)wrow*NH + krow);
      #pragma unroll
      for (int ks=0; ks<16; ks++){
        float4 lo = p4[ks*8], hi = p4[ks*8+1];             // 8 f32 at k = krow + ks*32
        short8 t;
        t[0]=(short)f2bf(lo.x); t[1]=(short)f2bf(lo.y); t[2]=(short)f2bf(lo.z); t[3]=(short)f2bf(lo.w);
        t[4]=(short)f2bf(hi.x); t[5]=(short)f2bf(hi.y); t[6]=(short)f2bf(hi.z); t[7]=(short)f2bf(hi.w);
        bw[h2][ks] = t;
      }
    }
  }

  // ---- epilogue identity: thread -> (row r_e, unit-pair up)
  int r_e = tid >> 4, up = tid & 15;
  int be = b0 + r_e;
  float cst0 = c0[be*NH + u0 + 2*up];
  float cst1 = c0[be*NH + u0 + 2*up + 1];

  // ---- step-invariant gate bias (base) into registers, once
  float2 bsv[4];
  #pragma unroll
  for (int gt=0; gt<4; gt++)
    bsv[gt] = *(const float2*)(base + (size_t)be*NG4 + gt*NH + u0 + 2*up);

  // ---- first token's table row into registers
  float2 tbv[4];
  {
    int tok0 = formulas[be*NT + 0];
    #pragma unroll
    for (int gt=0; gt<4; gt++)
      tbv[gt] = *(const float2*)(table + (size_t)tok0*NG4 + gt*NH + u0 + 2*up);
  }

  int arow = lane & 15;
  int abyte = arow*1024 + ((lane>>4)*8)*2;
  int aswz = (arow & 7) << 4;

  int* myflag = flags + g*16 + s;
  const int* pollptr = flags + g*16 + (lane & 15);

  for (int t=0; t<NT; t++){
    const uint32* hrd = hbuf + (t & 1)*HBUF_U;
    uint32*       hwr = hbuf + ((t+1) & 1)*HBUF_U;

    // ---- wait until all 16 producers have published h_t (relaxed polls only)
    if (t > 0){
      if (w == 0){
        int guard = 0;
        while (1){
          int v = __hip_atomic_load(pollptr, __ATOMIC_RELAXED, __HIP_MEMORY_SCOPE_AGENT);
          if (__all(v >= t)) break;
          __builtin_amdgcn_s_sleep(1);
          if (++guard > (1<<16)) break;   // safety bail-out
        }
      }
      __syncthreads();
    }

    // ---- stage group's h rows into LDS (swizzled)
    uint32 vals[16];
    #pragma unroll
    for (int it=0; it<16; it++){
      int i = tid + it*256;
      int r = i >> 8, cu = i & 255;
      vals[it] = __hip_atomic_load(&hrd[(b0+r)*(NH/2) + cu],
                                   __ATOMIC_RELAXED, __HIP_MEMORY_SCOPE_AGENT);
    }
    #pragma unroll
    for (int it=0; it<16; it++){
      int i = tid + it*256;
      int r = i >> 8, cu = i & 255;
      *(uint32*)(h_lds + ((r*1024 + cu*4) ^ ((r & 7) << 4))) = vals[it];
    }
    __syncthreads();

    // ---- MFMA: G_slice = h[16,512] @ Wslice.T
    f32x4 acc0 = {0.f,0.f,0.f,0.f}, acc1 = {0.f,0.f,0.f,0.f};
    #pragma unroll
    for (int ks=0; ks<16; ks++){
      short8 a = *(const short8*)(h_lds + ((abyte + ks*64) ^ aswz));
      acc0 = __builtin_amdgcn_mfma_f32_16x16x32_bf16(a, bw[0][ks], acc0, 0, 0, 0);
      acc1 = __builtin_amdgcn_mfma_f32_16x16x32_bf16(a, bw[1][ks], acc1, 0, 0, 0);
    }

    // ---- scatter acc -> G  (D: row=(lane>>4)*4+r, col=lane&15 per tile)
    {
      int rbase = (lane>>4)*4;
      int col0 = (w*2+0)*16 + (lane&15);
      int col1 = (w*2+1)*16 + (lane&15);
      #pragma unroll
      for (int r4=0;r4<4;r4++){
        G[(rbase+r4)*132 + col0] = acc0[r4];
        G[(rbase+r4)*132 + col1] = acc1[r4];
      }
    }
    __syncthreads();

    // ---- fused gate epilogue (2 units per thread), all operands in regs/LDS
    float hn0, hn1;
    {
      const float* Gr = G + r_e*132 + 2*up;
      float gi0 = Gr[0]   + tbv[0].x + bsv[0].x;
      float gi1 = Gr[1]   + tbv[0].y + bsv[0].y;
      float gf0 = Gr[32]  + tbv[1].x + bsv[1].x;
      float gf1 = Gr[33]  + tbv[1].y + bsv[1].y;
      float gg0 = Gr[64]  + tbv[2].x + bsv[2].x;
      float gg1 = Gr[65]  + tbv[2].y + bsv[2].y;
      float go0 = Gr[96]  + tbv[3].x + bsv[3].x;
      float go1 = Gr[97]  + tbv[3].y + bsv[3].y;
      float cn0 = sigf(gf0)*cst0 + sigf(gi0)*tanhfast(gg0);
      float cn1 = sigf(gf1)*cst1 + sigf(gi1)*tanhfast(gg1);
      cst0 = cn0; cst1 = cn1;
      hn0 = sigf(go0)*tanhfast(cn0);
      hn1 = sigf(go1)*tanhfast(cn1);
    }

    // ---- publish h_{t+1}: store (write-through to L3), drain, then flag
    if (t < NT-1){
      uint32 packed = (uint32)f2bf(hn0) | ((uint32)f2bf(hn1) << 16);
      __hip_atomic_store(&hwr[be*(NH/2) + (u0/2 + up)], packed,
                         __ATOMIC_RELAXED, __HIP_MEMORY_SCOPE_AGENT);
    }
    __syncthreads();   // vmcnt(0): h stores acked at L3 before flag
    if (t < NT-1 && tid == 0)
      __hip_atomic_store(myflag, t+1, __ATOMIC_RELAXED, __HIP_MEMORY_SCOPE_AGENT);

    // ---- off-critical-path: output store + next-token table prefetch
    {
      float2 ov; ov.x = hn0; ov.y = hn1;
      *(float2*)(out + ((size_t)be*NT + t)*NH + u0 + 2*up) = ov;
    }
    if (t < NT-1){
      int tokn = formulas[be*NT + t + 1];
      #pragma unroll
      for (int gt=0; gt<4; gt++)
        tbv[gt] = *(const float2*)(table + (size_t)tokn*NG4 + gt*NH + u0 + 2*up);
    }
  }
}

extern "C" void kernel_launch(void* const* d_in, const int* in_sizes, int n_in,
                              void* d_out, int out_size, void* d_ws, size_t ws_size,
                              hipStream_t stream) {
  const float* lat      = (const float*)d_in[0];
  const int*   formulas = (const int*)d_in[1];
  const float* emb      = (const float*)d_in[2];
  const float* Wih      = (const float*)d_in[3];
  const float* bih      = (const float*)d_in[4];
  const float* Whh      = (const float*)d_in[5];
  const float* bhh      = (const float*)d_in[6];
  const float* Wh       = (const float*)d_in[7];
  const float* bh       = (const float*)d_in[8];
  const float* Wc       = (const float*)d_in[9];
  const float* bc       = (const float*)d_in[10];
  const float* Wo       = (const float*)d_in[11];
  const float* bo       = (const float*)d_in[12];
  float* out = (float*)d_out;

  char* ws = (char*)d_ws;
  float* meanv = (float*)ws;  ws += (size_t)NB*NCH*4;        // 64 KB
  float* c0    = (float*)ws;  ws += (size_t)NB*NH*4;         // 256 KB
  float* o0    = (float*)ws;  ws += (size_t)NB*NH*4;         // 256 KB
  float* table = (float*)ws;  ws += (size_t)NV*NG4*4;        // 4 MB
  float* base  = (float*)ws;  ws += (size_t)NB*NG4*4;        // 1 MB
  uint32* hbuf = (uint32*)ws; ws += (size_t)2*HBUF_U*4;      // 256 KB (double-buffered)
  int*   flags = (int*)ws;    ws += 512;                     // 8 groups x 16 slices

  hipMemsetAsync(flags, 0, 512, stream);
  k_mean <<<NB, 256, 0, stream>>>(lat, meanv);
  k_init <<<NB, NH, 0, stream>>>(meanv, Wh, bh, Wc, bc, Wo, bo, c0, o0, (unsigned short*)hbuf);
  k_table<<<dim3(NV, 8), 256, 0, stream>>>(emb, Wih, table);
  k_base <<<dim3(NB, 8), 256, 0, stream>>>(o0, Wih, bih, bhh, base);
  k_lstm <<<NB, 256, 0, stream>>>(Whh, formulas, table, base, c0, hbuf, flags, out);
}